// Round 1
// baseline (609.632 us; speedup 1.0000x reference)
//
#include <hip/hip_runtime.h>
#include <hip/hip_bf16.h>

// AdEx reservoir: out[b][n] = v after 20 steps of
//   t  = min((v - vt[n]) / dt[n], 10)
//   we = beta[n] * exp(t)
//   dv = -alpha[n]*(v + 70) + I[b][n] - we
//   v  = v + 0.1*dv;  v = (v > vt[n]) ? vr[n] : v
// where I = x @ w_in.T.  NOTE: the reference's `w` state never feeds back
// into v and is not returned -> dead code, omitted entirely.

constexpr int kNeurons = 512;
constexpr int kInputs  = 21;
constexpr int kSteps   = 20;
constexpr int kBPB     = 8;   // batches per block

__global__ __launch_bounds__(kNeurons) void adex_kernel(
    const float* __restrict__ x,        // [B, 21]
    const float* __restrict__ alpha,    // [512]
    const float* __restrict__ beta,     // [512]
    const float* __restrict__ delta_t,  // [512]
    const float* __restrict__ w_in,     // [512, 21]
    const float* __restrict__ v_thresh, // [512]
    const float* __restrict__ v_reset,  // [512]
    float* __restrict__ out)            // [B, 512]
{
    const int n = threadIdx.x;                       // neuron id
    const long b0 = (long)blockIdx.x * kBPB;         // first batch of block

    // Stage this block's x rows (8 x 21 floats, contiguous) in LDS.
    __shared__ float x_s[kBPB * kInputs];
    if (threadIdx.x < kBPB * kInputs)
        x_s[threadIdx.x] = x[b0 * kInputs + threadIdx.x];

    // Per-neuron parameters -> registers (L1/L2-cached broadcast-ish loads).
    const float a  = alpha[n];
    const float be = beta[n];
    const float dt = delta_t[n];
    const float vt = v_thresh[n];
    const float vr = v_reset[n];

    // w_in row for this neuron -> 21 registers (read once per block,
    // w_in is 43 KB total -> L1/L2 resident across blocks).
    float w[kInputs];
#pragma unroll
    for (int k = 0; k < kInputs; ++k)
        w[k] = w_in[n * kInputs + k];

    __syncthreads();

    for (int g = 0; g < kBPB; ++g) {
        // Input projection for (batch b0+g, neuron n): 21-elem dot product.
        float I = 0.0f;
#pragma unroll
        for (int k = 0; k < kInputs; ++k)
            I += x_s[g * kInputs + k] * w[k];

        // 20-step AdEx recurrence, all in registers.
        float v = 0.0f;
#pragma unroll
        for (int s = 0; s < kSteps; ++s) {
            float t  = fminf((v - vt) / dt, 10.0f);  // IEEE div: match np closely
            float we = be * expf(t);                 // precise expf
            float dv = -a * (v + 70.0f) + I - we;
            v = v + dv * 0.1f;
            v = (v > vt) ? vr : v;                   // spike -> reset
        }
        out[(b0 + g) * kNeurons + n] = v;            // coalesced f32 store
    }
}

extern "C" void kernel_launch(void* const* d_in, const int* in_sizes, int n_in,
                              void* d_out, int out_size, void* d_ws, size_t ws_size,
                              hipStream_t stream) {
    const float* x        = (const float*)d_in[0];
    const float* alpha    = (const float*)d_in[1];
    const float* beta     = (const float*)d_in[2];
    const float* delta_t  = (const float*)d_in[3];
    const float* w_in     = (const float*)d_in[4];
    const float* v_thresh = (const float*)d_in[5];
    const float* v_reset  = (const float*)d_in[6];
    float* out = (float*)d_out;

    const int batch = in_sizes[0] / kInputs;         // 65536
    const int grid  = (batch + kBPB - 1) / kBPB;     // 8192 blocks

    adex_kernel<<<grid, kNeurons, 0, stream>>>(
        x, alpha, beta, delta_t, w_in, v_thresh, v_reset, out);
}

// Round 2
// 322.454 us; speedup vs baseline: 1.8906x; 1.8906x over previous
//
#include <hip/hip_runtime.h>
#include <hip/hip_bf16.h>

// AdEx reservoir: out[b][n] = v after 20 steps of
//   t  = min((v - vt[n]) / dt[n], 10)
//   we = beta[n] * exp(t)
//   dv = -alpha[n]*(v + 70) + I[b][n] - we
//   v  = v + 0.1*dv;  v = (v > vt[n]) ? vr[n] : v
// with I = x @ w_in.T.  `w` state is dead (never feeds back, not returned).
//
// R2: algebraic refactor to 7 VALU ops/step:
//   t2 = fma(v, log2e/dt, -vt*log2e/dt); t2 = min(t2, 10*log2e)
//   e  = exp2(t2)                         // single v_exp_f32
//   v' = fma(-0.1*beta, e, fma(1-0.1*alpha, v, 0.1*I - 7*alpha))
//   v  = v' > vt ? vr : v'
// x rows are block-uniform -> read from global with uniform addr (scalarizes
// to s_load; frees VALU + LDS pipes). No LDS, no __syncthreads.

constexpr int kNeurons = 512;
constexpr int kInputs  = 21;
constexpr int kSteps   = 20;
constexpr int kBPB     = 8;   // batches per block (one per wave-iteration)

__global__ __launch_bounds__(kNeurons) void adex_kernel(
    const float* __restrict__ x,        // [B, 21]
    const float* __restrict__ alpha,    // [512]
    const float* __restrict__ beta,     // [512]
    const float* __restrict__ delta_t,  // [512]
    const float* __restrict__ w_in,     // [512, 21]
    const float* __restrict__ v_thresh, // [512]
    const float* __restrict__ v_reset,  // [512]
    float* __restrict__ out)            // [B, 512]
{
    const int n = threadIdx.x;                       // neuron id
    const long b0 = (long)blockIdx.x * kBPB;         // first batch of block

    // Per-neuron parameters -> registers.
    const float a  = alpha[n];
    const float be = beta[n];
    const float dt = delta_t[n];
    const float vt = v_thresh[n];
    const float vr = v_reset[n];

    const float kLog2e = 1.44269504088896340736f;
    const float rdt  = kLog2e / dt;        // one div per thread, amortized
    const float tc   = -vt * rdt;          // t2 = v*rdt + tc
    const float tmax = 10.0f * kLog2e;     // clamp in exp2 domain
    const float k1   = 1.0f - 0.1f * a;    // Euler-folded decay
    const float ka   = 7.0f * a;           // 0.1 * alpha * 70
    const float bp   = 0.1f * be;          // 0.1 * beta (exp coefficient)

    // w_in row for this neuron -> 21 registers.
    float w[kInputs];
#pragma unroll
    for (int k = 0; k < kInputs; ++k)
        w[k] = w_in[n * kInputs + k];

    for (int g = 0; g < kBPB; ++g) {
        // Input projection: x row is uniform across the block -> SGPR loads.
        float I = 0.0f;
#pragma unroll
        for (int k = 0; k < kInputs; ++k)
            I += x[(b0 + g) * kInputs + k] * w[k];

        const float k2 = 0.1f * I - ka;

        float v = 0.0f;
#pragma unroll
        for (int s = 0; s < kSteps; ++s) {
            float t2 = fminf(fmaf(v, rdt, tc), tmax);   // v_fma + v_min
            float e  = exp2f(t2);                       // v_exp_f32
            float vn = fmaf(-bp, e, fmaf(k1, v, k2));   // 2x v_fma
            v = (vn > vt) ? vr : vn;                    // v_cmp + v_cndmask
        }
        out[(b0 + g) * kNeurons + n] = v;               // coalesced store
    }
}

extern "C" void kernel_launch(void* const* d_in, const int* in_sizes, int n_in,
                              void* d_out, int out_size, void* d_ws, size_t ws_size,
                              hipStream_t stream) {
    const float* x        = (const float*)d_in[0];
    const float* alpha    = (const float*)d_in[1];
    const float* beta     = (const float*)d_in[2];
    const float* delta_t  = (const float*)d_in[3];
    const float* w_in     = (const float*)d_in[4];
    const float* v_thresh = (const float*)d_in[5];
    const float* v_reset  = (const float*)d_in[6];
    float* out = (float*)d_out;

    const int batch = in_sizes[0] / kInputs;         // 65536
    const int grid  = (batch + kBPB - 1) / kBPB;     // 8192 blocks

    adex_kernel<<<grid, kNeurons, 0, stream>>>(
        x, alpha, beta, delta_t, w_in, v_thresh, v_reset, out);
}

// Round 3
// 262.697 us; speedup vs baseline: 2.3207x; 1.2275x over previous
//
#include <hip/hip_runtime.h>
#include <hip/hip_bf16.h>

// AdEx reservoir: out[b][n] = v after 20 steps of
//   t  = min((v - vt[n]) / dt[n], 10)
//   we = beta[n] * exp(t)
//   dv = -alpha[n]*(v + 70) + I[b][n] - we
//   v  = v + 0.1*dv;  v = (v > vt[n]) ? vr[n] : v
// with I = x @ w_in.T.  `w` state is dead (never feeds back, not returned).
//
// R3 changes vs R2 (arithmetic identical per chain):
//  1. exp2f -> __builtin_amdgcn_exp2f: bare v_exp_f32, no OCML wrapper.
//     Safe: t2 in [-36, 14.43] (v in [-70,10], rdt <= 0.72) -- never in the
//     denormal-fixup range, so results are bit-identical.
//  2. Loop order swapped to time-outer / batch-inner: 8 independent
//     recurrence chains live per wave -> ILP=8 hides v_exp latency and
//     packs the main VALU pipe.

constexpr int kNeurons = 512;
constexpr int kInputs  = 21;
constexpr int kSteps   = 20;
constexpr int kBPB     = 8;   // batches per block, interleaved in registers

__global__ __launch_bounds__(kNeurons) void adex_kernel(
    const float* __restrict__ x,        // [B, 21]
    const float* __restrict__ alpha,    // [512]
    const float* __restrict__ beta,     // [512]
    const float* __restrict__ delta_t,  // [512]
    const float* __restrict__ w_in,     // [512, 21]
    const float* __restrict__ v_thresh, // [512]
    const float* __restrict__ v_reset,  // [512]
    float* __restrict__ out)            // [B, 512]
{
    const int n = threadIdx.x;                       // neuron id
    const long b0 = (long)blockIdx.x * kBPB;         // first batch of block

    // Per-neuron parameters -> registers.
    const float a  = alpha[n];
    const float be = beta[n];
    const float dt = delta_t[n];
    const float vt = v_thresh[n];
    const float vr = v_reset[n];

    const float kLog2e = 1.44269504088896340736f;
    const float rdt  = kLog2e / dt;        // one div per thread, amortized
    const float tc   = -vt * rdt;          // t2 = v*rdt + tc
    const float tmax = 10.0f * kLog2e;     // clamp in exp2 domain
    const float k1   = 1.0f - 0.1f * a;    // Euler-folded decay
    const float ka   = 7.0f * a;           // 0.1 * alpha * 70
    const float bp   = 0.1f * be;          // 0.1 * beta (exp coefficient)

    // w_in row for this neuron -> 21 registers.
    float w[kInputs];
#pragma unroll
    for (int k = 0; k < kInputs; ++k)
        w[k] = w_in[n * kInputs + k];

    // Input projection for all 8 batches (x rows are block-uniform -> s_load).
    float k2[kBPB];
#pragma unroll
    for (int g = 0; g < kBPB; ++g) {
        float I = 0.0f;
#pragma unroll
        for (int k = 0; k < kInputs; ++k)
            I = fmaf(x[(b0 + g) * kInputs + k], w[k], I);
        k2[g] = 0.1f * I - ka;
    }

    // 20-step recurrence, 8 interleaved independent chains (ILP=8).
    float v[kBPB];
#pragma unroll
    for (int g = 0; g < kBPB; ++g) v[g] = 0.0f;

#pragma unroll
    for (int s = 0; s < kSteps; ++s) {
#pragma unroll
        for (int g = 0; g < kBPB; ++g) {
            float t2 = fminf(fmaf(v[g], rdt, tc), tmax);   // v_fma + v_min
            float e  = __builtin_amdgcn_exp2f(t2);         // bare v_exp_f32
            float vn = fmaf(-bp, e, fmaf(k1, v[g], k2[g])); // 2x v_fma
            v[g] = (vn > vt) ? vr : vn;                    // v_cmp + v_cndmask
        }
    }

#pragma unroll
    for (int g = 0; g < kBPB; ++g)
        out[(b0 + g) * kNeurons + n] = v[g];               // coalesced stores

}

extern "C" void kernel_launch(void* const* d_in, const int* in_sizes, int n_in,
                              void* d_out, int out_size, void* d_ws, size_t ws_size,
                              hipStream_t stream) {
    const float* x        = (const float*)d_in[0];
    const float* alpha    = (const float*)d_in[1];
    const float* beta     = (const float*)d_in[2];
    const float* delta_t  = (const float*)d_in[3];
    const float* w_in     = (const float*)d_in[4];
    const float* v_thresh = (const float*)d_in[5];
    const float* v_reset  = (const float*)d_in[6];
    float* out = (float*)d_out;

    const int batch = in_sizes[0] / kInputs;         // 65536
    const int grid  = (batch + kBPB - 1) / kBPB;     // 8192 blocks

    adex_kernel<<<grid, kNeurons, 0, stream>>>(
        x, alpha, beta, delta_t, w_in, v_thresh, v_reset, out);
}